// Round 2
// baseline (135.943 us; speedup 1.0000x reference)
//
#include <hip/hip_runtime.h>
#include <hip/hip_bf16.h>

#define B_N 2048
#define D_V 8
#define F_D 256
#define TILE 128
#define BC 64
#define LSTR 258   // 258 shorts = 129 dwords == 1 (mod 32) -> 2-way (free) b128 reads

// sqrt(2*log2(e)) : zn scaled by this => MFMA acc = 2*log2(e)*dot => exp(2*dot) = exp2(acc)
#define SCALE_F 1.69864364f

#if defined(__has_builtin)
#  if __has_builtin(__builtin_amdgcn_exp2f)
#    define EXP2F(x) __builtin_amdgcn_exp2f(x)
#  else
#    define EXP2F(x) exp2f(x)
#  endif
#else
#  define EXP2F(x) exp2f(x)
#endif

typedef __attribute__((ext_vector_type(8))) short short8;
typedef __attribute__((ext_vector_type(4))) float floatx4;

__device__ inline unsigned short f2bf(float f) {
    __hip_bfloat16 h = __float2bfloat16(f);
    return *reinterpret_cast<unsigned short*>(&h);
}

__device__ inline float wave_reduce_sum(float v) {
    #pragma unroll
    for (int off = 1; off < 64; off <<= 1)
        v += __shfl_xor(v, off, 64);
    return v;
}

// ---------------------------------------------------------------------------
// Kernel 1: normalize each (b,d) row of 256 floats; write bf16 zn (pre-scaled
// by SCALE_F) in [d][b][f] layout. One wave per row (16384 waves -> fully
// latency-hidden). Also zero-inits ns8[8][2048].
// ---------------------------------------------------------------------------
__global__ void norm_kernel(const float* __restrict__ z,
                            unsigned short* __restrict__ zn,
                            float* __restrict__ ns8) {
    int gid = blockIdx.x * blockDim.x + threadIdx.x;
    if (gid < D_V * B_N) ns8[gid] = 0.0f;
    int wave = gid >> 6;  // row = b*8+d
    int lane = threadIdx.x & 63;
    const float4* zp = (const float4*)(z + (size_t)wave * F_D);
    float4 v = zp[lane];
    float ss = v.x * v.x + v.y * v.y + v.z * v.z + v.w * v.w;
    ss = wave_reduce_sum(ss);
    float inv = SCALE_F / fmaxf(sqrtf(ss), 1e-12f);
    int b = wave >> 3, d = wave & 7;
    unsigned short* op = zn + (size_t)d * (B_N * F_D) + (size_t)b * F_D + lane * 4;
    ushort4 o;
    o.x = f2bf(v.x * inv);
    o.y = f2bf(v.y * inv);
    o.z = f2bf(v.z * inv);
    o.w = f2bf(v.w * inv);
    *(ushort4*)op = o;
}

// ---------------------------------------------------------------------------
// Kernel 2: pos[b] = sum_{d!=e} exp(2*dot(zn[b,d], zn[b,e]))
// One wave handles 2 samples: 16 rows = [s0 views 0..7 | s1 views 0..7].
// acc already = 2*log2e*dot -> single v_exp.
// ---------------------------------------------------------------------------
__global__ void pos_kernel(const unsigned short* __restrict__ zn,
                           float* __restrict__ pos) {
    int gw = (blockIdx.x * blockDim.x + threadIdx.x) >> 6;
    int lane = threadIdx.x & 63;
    int q = lane >> 4, li = lane & 15;
    int s0 = gw * 2;
    int b = s0 + (li >> 3), d = li & 7;
    const unsigned short* rowp = zn + (size_t)d * (B_N * F_D) + (size_t)b * F_D;
    short8 a[8];
    #pragma unroll
    for (int kk = 0; kk < 8; kk++)
        a[kk] = *(const short8*)(rowp + kk * 32 + q * 8);
    floatx4 acc = {0.f, 0.f, 0.f, 0.f};
    #pragma unroll
    for (int kk = 0; kk < 8; kk++)
        acc = __builtin_amdgcn_mfma_f32_16x16x32_bf16(a[kk], a[kk], acc, 0, 0, 0);
    float p0 = 0.f, p1 = 0.f;
    #pragma unroll
    for (int r = 0; r < 4; r++) {
        int row = q * 4 + r, col = li;
        bool same_sample = (row >> 3) == (col >> 3);
        if (same_sample && row != col) {
            float e = EXP2F(acc[r]);
            if (row < 8) p0 += e; else p1 += e;
        }
    }
    p0 = wave_reduce_sum(p0);
    p1 = wave_reduce_sum(p1);
    if (lane == 0) { pos[s0] = p0; pos[s0 + 1] = p1; }
}

// ---------------------------------------------------------------------------
// Kernel 3 (symmetric-halved): per view d, for upper-triangle 128x128 tiles
// (i<=j) of S = exp(2 * Z Z^T): row-sums -> ns8[d][i*128+..]; for off-diag
// tiles also col-sums -> ns8[d][j*128+..] (covers the mirrored tile).
// Block = 256 threads (4 waves); each wave owns 32 A-rows (2 MFMA row-sets,
// K=256 resident in 64 VGPRs). B staged in LDS 64 cols at a time.
// 4 waves/block doubles TLP vs the 2-wave version: 4352 waves ~ 4.25/SIMD.
// ---------------------------------------------------------------------------
__global__ __launch_bounds__(256)
void neg_kernel(const unsigned short* __restrict__ zn,
                float* __restrict__ ns8) {
    __shared__ __align__(16) unsigned short Bs[BC * LSTR];  // 33 KB -> 4 blocks/CU
    const int d = blockIdx.y;
    int trem = blockIdx.x;            // 0..135 -> (i,j), i<=j
    int i = 0;
    while (trem >= 16 - i) { trem -= 16 - i; ++i; }
    const int j = i + trem;
    const bool diag = (i == j);
    const unsigned short* Z = zn + (size_t)d * (B_N * F_D);
    int tid = threadIdx.x, w = tid >> 6, lane = tid & 63;
    int q = lane >> 4, li = lane & 15;
    int r0 = i * TILE + w * 32;       // this wave's 32 A-rows

    short8 a[2][8];                   // 64 VGPRs, resident whole kernel
    #pragma unroll
    for (int s = 0; s < 2; s++)
        #pragma unroll
        for (int kk = 0; kk < 8; kk++)
            a[s][kk] = *(const short8*)(Z + (size_t)(r0 + s * 16 + li) * F_D + kk * 32 + q * 8);

    float rs[2][4];
    #pragma unroll
    for (int s = 0; s < 2; s++)
        #pragma unroll
        for (int r = 0; r < 4; r++) rs[s][r] = 0.f;
    float cs[8];

    #pragma unroll
    for (int stage = 0; stage < 2; ++stage) {
        int c0 = j * TILE + stage * BC;
        __syncthreads();
        // stage 64 rows x 256 shorts: 2048 16B-chunks, 8 per thread (coalesced)
        #pragma unroll
        for (int it = 0; it < 8; ++it) {
            int idx = it * 256 + tid;
            int row = idx >> 5, kc = idx & 31;
            *(short8*)(&Bs[row * LSTR + kc * 8]) =
                *(const short8*)(Z + (size_t)(c0 + row) * F_D + kc * 8);
        }
        __syncthreads();
        #pragma unroll
        for (int ct = 0; ct < 4; ++ct) {
            const unsigned short* bp = &Bs[(ct * 16 + li) * LSTR + q * 8];
            floatx4 acc[2];
            acc[0] = (floatx4){0.f, 0.f, 0.f, 0.f};
            acc[1] = (floatx4){0.f, 0.f, 0.f, 0.f};
            // per-kk bf load keeps live B-frags small (VGPR ~120 -> 4 waves/SIMD)
            #pragma unroll
            for (int kk = 0; kk < 8; kk++) {
                short8 bf = *(const short8*)(bp + kk * 32);
                acc[0] = __builtin_amdgcn_mfma_f32_16x16x32_bf16(a[0][kk], bf, acc[0], 0, 0, 0);
                acc[1] = __builtin_amdgcn_mfma_f32_16x16x32_bf16(a[1][kk], bf, acc[1], 0, 0, 0);
            }
            // C/D layout: col = li, row(within set) = q*4 + r
            int gcol = c0 + ct * 16 + li;
            float csum = 0.f;
            #pragma unroll
            for (int s = 0; s < 2; s++) {
                #pragma unroll
                for (int r = 0; r < 4; r++) {
                    float e = EXP2F(acc[s][r]);        // exp(2*dot), 1 trans op
                    if (diag) {                        // uniform branch: 16/136 blocks
                        int grow = r0 + s * 16 + q * 4 + r;
                        if (grow == gcol) e = 0.f;
                    }
                    rs[s][r] += e;
                    csum += e;
                }
            }
            cs[stage * 4 + ct] = csum;  // static index (loops unrolled)
        }
    }

    // row sums: reduce across the 16 column-lanes; lanes li<8 each own one
    // (s,r) value and issue one atomic
    #pragma unroll
    for (int off = 1; off < 16; off <<= 1)
        #pragma unroll
        for (int s = 0; s < 2; s++)
            #pragma unroll
            for (int r = 0; r < 4; r++)
                rs[s][r] += __shfl_xor(rs[s][r], off, 64);
    {
        float rv = 0.f;
        #pragma unroll
        for (int s = 0; s < 2; s++)
            #pragma unroll
            for (int r = 0; r < 4; r++)
                if (li == s * 4 + r) rv = rs[s][r];
        if (li < 8)
            atomicAdd(&ns8[d * B_N + r0 + (li >> 2) * 16 + q * 4 + (li & 3)], rv);
    }

    // col sums (mirrored tile coverage): cross-q reduce; each wave atomics its
    // own 32-row contribution (4 waves -> 4 atomics/column, negligible)
    if (!diag) {
        #pragma unroll
        for (int c = 0; c < 8; c++) {
            cs[c] += __shfl_xor(cs[c], 16, 64);
            cs[c] += __shfl_xor(cs[c], 32, 64);
        }
        float v0 = 0.f, v1 = 0.f;
        #pragma unroll
        for (int c = 0; c < 4; c++)
            if (q == c) { v0 = cs[c]; v1 = cs[c + 4]; }
        atomicAdd(&ns8[d * B_N + j * TILE + q * 16 + li], v0);
        atomicAdd(&ns8[d * B_N + j * TILE + 64 + q * 16 + li], v1);
    }
}

// ---------------------------------------------------------------------------
// Kernel 4: neg[b] = sum_d ns8[d][b] / (B-1); logits = pos/(pos+neg);
// loss = max + log(sum exp(l-max)) - mean(l)
// ---------------------------------------------------------------------------
__global__ void final_kernel(const float* __restrict__ pos,
                             const float* __restrict__ ns8,
                             float* __restrict__ out) {
    __shared__ float red[256];
    int t = threadIdx.x;
    float vals[8];
    float lmax = -1e30f;
    #pragma unroll
    for (int i = 0; i < 8; i++) {
        int idx = t * 8 + i;
        float nsum = 0.f;
        #pragma unroll
        for (int d = 0; d < D_V; d++) nsum += ns8[d * B_N + idx];
        float p = pos[idx];
        float n = nsum * (1.0f / (float)(B_N - 1));
        float l = p / (p + n);
        vals[i] = l;
        lmax = fmaxf(lmax, l);
    }
    red[t] = lmax; __syncthreads();
    for (int s = 128; s > 0; s >>= 1) {
        if (t < s) red[t] = fmaxf(red[t], red[t + s]);
        __syncthreads();
    }
    float m = red[0]; __syncthreads();
    float se = 0.f, sl = 0.f;
    #pragma unroll
    for (int i = 0; i < 8; i++) { se += expf(vals[i] - m); sl += vals[i]; }
    red[t] = se; __syncthreads();
    for (int s = 128; s > 0; s >>= 1) {
        if (t < s) red[t] += red[t + s];
        __syncthreads();
    }
    float S = red[0]; __syncthreads();
    red[t] = sl; __syncthreads();
    for (int s = 128; s > 0; s >>= 1) {
        if (t < s) red[t] += red[t + s];
        __syncthreads();
    }
    if (t == 0) out[0] = m + logf(S) - red[0] / (float)B_N;
}

extern "C" void kernel_launch(void* const* d_in, const int* in_sizes, int n_in,
                              void* d_out, int out_size, void* d_ws, size_t ws_size,
                              hipStream_t stream) {
    const float* z = (const float*)d_in[0];
    float* out = (float*)d_out;
    unsigned short* zn = (unsigned short*)d_ws;                        // 8 MB bf16 (pre-scaled)
    float* ns8 = (float*)((char*)d_ws + (size_t)D_V * B_N * F_D * 2);  // 64 KB
    float* pos = ns8 + D_V * B_N;                                      // 8 KB

    norm_kernel<<<dim3(4096), 256, 0, stream>>>(z, zn, ns8);
    pos_kernel<<<dim3(256), 256, 0, stream>>>(zn, pos);
    neg_kernel<<<dim3(136, 8), 256, 0, stream>>>(zn, ns8);
    final_kernel<<<1, 256, 0, stream>>>(pos, ns8, out);
}

// Round 3
// 107.461 us; speedup vs baseline: 1.2650x; 1.2650x over previous
//
#include <hip/hip_runtime.h>
#include <hip/hip_bf16.h>

#define B_N 2048
#define D_V 8
#define F_D 256

// sqrt(2*log2(e)) : zn scaled by this => MFMA acc = 2*log2(e)*dot => exp(2*dot) = exp2(acc)
#define SCALE_F 1.69864364f

#if defined(__has_builtin)
#  if __has_builtin(__builtin_amdgcn_exp2f)
#    define EXP2F(x) __builtin_amdgcn_exp2f(x)
#  else
#    define EXP2F(x) exp2f(x)
#  endif
#else
#  define EXP2F(x) exp2f(x)
#endif

typedef __attribute__((ext_vector_type(8))) short short8;
typedef __attribute__((ext_vector_type(4))) float floatx4;

__device__ inline unsigned short f2bf(float f) {
    __hip_bfloat16 h = __float2bfloat16(f);
    return *reinterpret_cast<unsigned short*>(&h);
}

__device__ inline float wave_reduce_sum(float v) {
    #pragma unroll
    for (int off = 1; off < 64; off <<= 1)
        v += __shfl_xor(v, off, 64);
    return v;
}

// ---------------------------------------------------------------------------
// Kernel 1: normalize each (b,d) row of 256 floats; write bf16 zn (pre-scaled
// by SCALE_F) in [d][b][f] layout. One wave per row (16384 waves -> fully
// latency-hidden). Also zero-inits ns8[8][2048].
// ---------------------------------------------------------------------------
__global__ void norm_kernel(const float* __restrict__ z,
                            unsigned short* __restrict__ zn,
                            float* __restrict__ ns8) {
    int gid = blockIdx.x * blockDim.x + threadIdx.x;
    if (gid < D_V * B_N) ns8[gid] = 0.0f;
    int wave = gid >> 6;  // row = b*8+d
    int lane = threadIdx.x & 63;
    const float4* zp = (const float4*)(z + (size_t)wave * F_D);
    float4 v = zp[lane];
    float ss = v.x * v.x + v.y * v.y + v.z * v.z + v.w * v.w;
    ss = wave_reduce_sum(ss);
    float inv = SCALE_F / fmaxf(sqrtf(ss), 1e-12f);
    int b = wave >> 3, d = wave & 7;
    unsigned short* op = zn + (size_t)d * (B_N * F_D) + (size_t)b * F_D + lane * 4;
    ushort4 o;
    o.x = f2bf(v.x * inv);
    o.y = f2bf(v.y * inv);
    o.z = f2bf(v.z * inv);
    o.w = f2bf(v.w * inv);
    *(ushort4*)op = o;
}

// ---------------------------------------------------------------------------
// Kernel 2: pos[b] = sum_{d!=e} exp(2*dot(zn[b,d], zn[b,e]))
// One wave handles 2 samples: 16 rows = [s0 views 0..7 | s1 views 0..7].
// acc already = 2*log2e*dot -> single v_exp.
// ---------------------------------------------------------------------------
__global__ void pos_kernel(const unsigned short* __restrict__ zn,
                           float* __restrict__ pos) {
    int gw = (blockIdx.x * blockDim.x + threadIdx.x) >> 6;
    int lane = threadIdx.x & 63;
    int q = lane >> 4, li = lane & 15;
    int s0 = gw * 2;
    int b = s0 + (li >> 3), d = li & 7;
    const unsigned short* rowp = zn + (size_t)d * (B_N * F_D) + (size_t)b * F_D;
    short8 a[8];
    #pragma unroll
    for (int kk = 0; kk < 8; kk++)
        a[kk] = *(const short8*)(rowp + kk * 32 + q * 8);
    floatx4 acc = {0.f, 0.f, 0.f, 0.f};
    #pragma unroll
    for (int kk = 0; kk < 8; kk++)
        acc = __builtin_amdgcn_mfma_f32_16x16x32_bf16(a[kk], a[kk], acc, 0, 0, 0);
    float p0 = 0.f, p1 = 0.f;
    #pragma unroll
    for (int r = 0; r < 4; r++) {
        int row = q * 4 + r, col = li;
        bool same_sample = (row >> 3) == (col >> 3);
        if (same_sample && row != col) {
            float e = EXP2F(acc[r]);
            if (row < 8) p0 += e; else p1 += e;
        }
    }
    p0 = wave_reduce_sum(p0);
    p1 = wave_reduce_sum(p1);
    if (lane == 0) { pos[s0] = p0; pos[s0 + 1] = p1; }
}

// ---------------------------------------------------------------------------
// Kernel 3 (symmetric-halved, LDS-FREE, barrier-free): per view d, one WAVE
// per upper-triangle 64x64 tile (i<=j) of S = exp(2 * Z Z^T).
// Row-sums -> ns8[d][i*64+..]; off-diag tiles also col-sums -> ns8[d][j*64+..]
// (covers the mirrored tile). A-frags (128 VGPR) and B-frags are read
// DIRECTLY from global: per-view plane is 1 MB, L2-resident on its pinned
// XCD (1-D grid, d = bid&7 matches round-robin XCD dispatch). No __shared__,
// no __syncthreads -> all 4224 waves fully independent; latency hidden by
// TLP (2 waves/SIMD at ~210 VGPR) instead of intra-block pipelining.
// ---------------------------------------------------------------------------
__global__ __launch_bounds__(64, 2)
void neg_kernel(const unsigned short* __restrict__ zn,
                float* __restrict__ ns8) {
    const int bid = blockIdx.x;
    const int d = bid & 7;            // view == XCD (perf heuristic only)
    int t = bid >> 3;                 // 0..527 -> (i,j), i<=j, 32 tile-rows
    int i = 0;
    while (t >= 32 - i) { t -= 32 - i; ++i; }
    const int j = i + t;
    const bool diag = (i == j);
    const unsigned short* Z = zn + (size_t)d * (B_N * F_D);
    int lane = threadIdx.x & 63;
    int q = lane >> 4, li = lane & 15;
    int r0 = i * 64, c0 = j * 64;

    short8 a[4][8];                   // 128 VGPR, resident whole kernel
    #pragma unroll
    for (int s = 0; s < 4; s++)
        #pragma unroll
        for (int kk = 0; kk < 8; kk++)
            a[s][kk] = *(const short8*)(Z + (size_t)(r0 + s * 16 + li) * F_D + kk * 32 + q * 8);

    float rs[4][4];
    #pragma unroll
    for (int s = 0; s < 4; s++)
        #pragma unroll
        for (int r = 0; r < 4; r++) rs[s][r] = 0.f;
    float cs[4];

    #pragma unroll
    for (int ct = 0; ct < 4; ++ct) {
        // B-frags straight from L2 (no LDS round-trip)
        short8 bf[8];
        #pragma unroll
        for (int kk = 0; kk < 8; kk++)
            bf[kk] = *(const short8*)(Z + (size_t)(c0 + ct * 16 + li) * F_D + kk * 32 + q * 8);
        floatx4 acc[4];
        #pragma unroll
        for (int s = 0; s < 4; s++) acc[s] = (floatx4){0.f, 0.f, 0.f, 0.f};
        #pragma unroll
        for (int kk = 0; kk < 8; kk++)
            #pragma unroll
            for (int s = 0; s < 4; s++)
                acc[s] = __builtin_amdgcn_mfma_f32_16x16x32_bf16(a[s][kk], bf[kk], acc[s], 0, 0, 0);
        // C/D layout: col = li, row(within set) = q*4 + r
        int gcol = c0 + ct * 16 + li;
        float csum = 0.f;
        #pragma unroll
        for (int s = 0; s < 4; s++) {
            #pragma unroll
            for (int r = 0; r < 4; r++) {
                float e = EXP2F(acc[s][r]);        // exp(2*dot), 1 trans op
                if (diag) {                        // uniform branch: 32/528 tiles
                    int grow = r0 + s * 16 + q * 4 + r;
                    if (grow == gcol) e = 0.f;
                }
                rs[s][r] += e;
                csum += e;
            }
        }
        cs[ct] = csum;                 // static index (loop unrolled)
    }

    // row sums: reduce across the 16 column-lanes, then each lane owns one
    // of the 64 rows: row = (li>>2)*16 + q*4 + (li&3)
    #pragma unroll
    for (int off = 1; off < 16; off <<= 1)
        #pragma unroll
        for (int s = 0; s < 4; s++)
            #pragma unroll
            for (int r = 0; r < 4; r++)
                rs[s][r] += __shfl_xor(rs[s][r], off, 64);
    {
        float rv = 0.f;
        #pragma unroll
        for (int s = 0; s < 4; s++)
            #pragma unroll
            for (int r = 0; r < 4; r++)
                if (li == s * 4 + r) rv = rs[s][r];
        atomicAdd(&ns8[d * B_N + r0 + (li >> 2) * 16 + q * 4 + (li & 3)], rv);
    }

    // col sums (mirrored tile coverage): cross-q reduce, lane (q,li) owns
    // col q*16+li via cs[q]
    if (!diag) {
        #pragma unroll
        for (int c = 0; c < 4; c++) {
            cs[c] += __shfl_xor(cs[c], 16, 64);
            cs[c] += __shfl_xor(cs[c], 32, 64);
        }
        float v = 0.f;
        #pragma unroll
        for (int c = 0; c < 4; c++)
            if (q == c) v = cs[c];
        atomicAdd(&ns8[d * B_N + c0 + q * 16 + li], v);
    }
}

// ---------------------------------------------------------------------------
// Kernel 4: neg[b] = sum_d ns8[d][b] / (B-1); logits = pos/(pos+neg);
// loss = max + log(sum exp(l-max)) - mean(l)
// ---------------------------------------------------------------------------
__global__ void final_kernel(const float* __restrict__ pos,
                             const float* __restrict__ ns8,
                             float* __restrict__ out) {
    __shared__ float red[256];
    int t = threadIdx.x;
    float vals[8];
    float lmax = -1e30f;
    #pragma unroll
    for (int i = 0; i < 8; i++) {
        int idx = t * 8 + i;
        float nsum = 0.f;
        #pragma unroll
        for (int d = 0; d < D_V; d++) nsum += ns8[d * B_N + idx];
        float p = pos[idx];
        float n = nsum * (1.0f / (float)(B_N - 1));
        float l = p / (p + n);
        vals[i] = l;
        lmax = fmaxf(lmax, l);
    }
    red[t] = lmax; __syncthreads();
    for (int s = 128; s > 0; s >>= 1) {
        if (t < s) red[t] = fmaxf(red[t], red[t + s]);
        __syncthreads();
    }
    float m = red[0]; __syncthreads();
    float se = 0.f, sl = 0.f;
    #pragma unroll
    for (int i = 0; i < 8; i++) { se += expf(vals[i] - m); sl += vals[i]; }
    red[t] = se; __syncthreads();
    for (int s = 128; s > 0; s >>= 1) {
        if (t < s) red[t] += red[t + s];
        __syncthreads();
    }
    float S = red[0]; __syncthreads();
    red[t] = sl; __syncthreads();
    for (int s = 128; s > 0; s >>= 1) {
        if (t < s) red[t] += red[t + s];
        __syncthreads();
    }
    if (t == 0) out[0] = m + logf(S) - red[0] / (float)B_N;
}

extern "C" void kernel_launch(void* const* d_in, const int* in_sizes, int n_in,
                              void* d_out, int out_size, void* d_ws, size_t ws_size,
                              hipStream_t stream) {
    const float* z = (const float*)d_in[0];
    float* out = (float*)d_out;
    unsigned short* zn = (unsigned short*)d_ws;                        // 8 MB bf16 (pre-scaled)
    float* ns8 = (float*)((char*)d_ws + (size_t)D_V * B_N * F_D * 2);  // 64 KB
    float* pos = ns8 + D_V * B_N;                                      // 8 KB

    norm_kernel<<<dim3(4096), 256, 0, stream>>>(z, zn, ns8);
    pos_kernel<<<dim3(256), 256, 0, stream>>>(zn, pos);
    neg_kernel<<<dim3(528 * 8), 64, 0, stream>>>(zn, ns8);
    final_kernel<<<1, 256, 0, stream>>>(pos, ns8, out);
}